// Round 1
// 391.589 us; speedup vs baseline: 1.0649x; 1.0649x over previous
//
#include <hip/hip_runtime.h>
#include <stdint.h>

typedef int v4i __attribute__((ext_vector_type(4)));

constexpr int K_DIM = 4096;
constexpr int N_DIM = 4096;
constexpr int TM = 128;
constexpr int TN = 128;
constexpr int TK = 128;              // two i8 MFMA K-steps per barrier pair
constexpr int KSTEPS = K_DIM / TK;   // 32

// pack low bytes of 4 int32 (each holding one int8 value) into one dword
__device__ __forceinline__ int pack4(int a, int b, int c, int d) {
    unsigned r = (unsigned(a) & 0xFFu)
               | ((unsigned(b) & 0xFFu) << 8)
               | ((unsigned(c) & 0xFFu) << 16)
               | (unsigned(d) << 24);
    return (int)r;
}

// ---------------- pre-pack: int8-in-int32 -> packed int8 (fused X+W) -------
__global__ __launch_bounds__(256) void pack_both(
    const int* __restrict__ s1, int* __restrict__ d1, int n1,   // dwords out
    const int* __restrict__ s2, int* __restrict__ d2, int n2)
{
    int idx = blockIdx.x * blockDim.x + threadIdx.x;
    const int* s;
    int* d;
    if (idx < n1) { s = s1; d = d1; }
    else if (idx < n1 + n2) { s = s2; d = d2; idx -= n1; }
    else return;
    v4i v = ((const v4i*)s)[idx];
    d[idx] = pack4(v.x, v.y, v.z, v.w);
}

// async global->LDS, 16 B per lane. LDS dest = wave-uniform base + lane*16.
__device__ __forceinline__ void gld16(const int8_t* g, int8_t* l) {
    __builtin_amdgcn_global_load_lds(
        (const __attribute__((address_space(1))) char*)g,
        (__attribute__((address_space(3))) char*)l,
        16, 0, 0);
}

// ================= 256x256 8-wave pipelined GEMM (T1+T4+T5) =================
// C[m][n] = alpha * sum_k X[m][k]*W[n][k] + bias[n]
// 8 waves (2M x 4N), per-wave output 128x64 = 8x4 frags of 16x16.
// BK = 128 bytes/K-tile, double-buffered LDS (2 x (A 32K + B 32K) = 128 KB).
// Chunk swizzle: slot s of row r holds global k-chunk s ^ ((r>>1)&7);
// reading k-half kk just XORs the LDS offset with kk<<6 (verified layout).
// Pipeline per tile t: issue A(t+1) -> vmcnt(4) (tile t landed, A(t+1) stays
// in flight) -> barrier -> ksub0 reads+32 MFMA -> issue B(t+1) -> ksub1
// reads+32 MFMA -> barrier. vmcnt never drains to 0 in the main loop.
constexpr int BM = 256;
constexpr int BN = 256;
constexpr int BKB = 128;
constexpr int KT = K_DIM / BKB;      // 32

__global__ __launch_bounds__(512, 2) void w8a8_gemm_256(
    const int8_t* __restrict__ X,     // [M][K] int8 packed
    const int8_t* __restrict__ Wt,    // [N][K] int8 packed (B^T)
    const float*  __restrict__ bias,  // [N]
    const float*  __restrict__ alphap,
    float* __restrict__ Y)            // [M][N] fp32
{
    extern __shared__ __align__(128) int8_t smem[];   // 2 x {A 32K, B 32K}

    const int tid  = threadIdx.x;
    const int lane = tid & 63;
    const int wave = tid >> 6;

    // XCD-aware bijective swizzle: 512 blocks, 64 per XCD, column-major tiles
    const int flat = blockIdx.x;
    const int swz  = (flat & 7) * 64 + (flat >> 3);
    const int m0   = (swz & 31) * BM;
    const int n0   = (swz >> 5) * BN;

    // ---- staging geometry: 2048 chunks/tile/matrix, 4 issue rounds ----
    int ag[4], bg[4], ldso[4];        // 32-bit global offsets (fit: M*K < 2^31)
#pragma unroll
    for (int q = 0; q < 4; ++q) {
        const int c   = q * 512 + tid;
        const int row = c >> 3;
        const int gko = ((c & 7) ^ ((row >> 1) & 7)) << 4;
        ag[q]   = (m0 + row) * K_DIM + gko;
        bg[q]   = (n0 + row) * K_DIM + gko;
        ldso[q] = c << 4;
    }

    // ---- compute geometry ----
    const int wm   = (wave & 1) << 7;   // 0 / 128
    const int wn   = (wave >> 1) << 6;  // 0 / 64 / 128 / 192
    const int lrow = lane & 15;
    const int quad = lane >> 4;

    int a_off[8], b_off[4];             // ksub0 offsets; ksub1 = ^64
#pragma unroll
    for (int i = 0; i < 8; ++i) {
        const int ra = wm + i * 16 + lrow;
        a_off[i] = ra * BKB + ((quad ^ ((ra >> 1) & 7)) << 4);
    }
#pragma unroll
    for (int j = 0; j < 4; ++j) {
        const int rb = wn + j * 16 + lrow;
        b_off[j] = rb * BKB + ((quad ^ ((rb >> 1) & 7)) << 4);
    }

    v4i acc[8][4] = {};

    // ---- prologue: stage tile 0 into buffer 0 ----
#pragma unroll
    for (int q = 0; q < 4; ++q) gld16(X  + ag[q], smem + ldso[q]);
#pragma unroll
    for (int q = 0; q < 4; ++q) gld16(Wt + bg[q], smem + 32768 + ldso[q]);

    for (int t = 0; t < KT; ++t) {
        int8_t* Ard = smem + ((t & 1) << 16);
        int8_t* Brd = Ard + 32768;
        const int kb1 = (t + 1) * BKB;

        if (t + 1 < KT) {
            int8_t* Awr = smem + (((t + 1) & 1) << 16);
#pragma unroll
            for (int q = 0; q < 4; ++q) gld16(X + ag[q] + kb1, Awr + ldso[q]);
            // oldest 8 (tile t's A+B) land; A(t+1) stays in flight
            asm volatile("s_waitcnt vmcnt(4)" ::: "memory");
        } else {
            asm volatile("s_waitcnt vmcnt(0)" ::: "memory");
        }
        asm volatile("s_barrier" ::: "memory");

        v4i a[8], b[4];
        // ---- ksub 0 ----
#pragma unroll
        for (int i = 0; i < 8; ++i) a[i] = *(const v4i*)(Ard + a_off[i]);
#pragma unroll
        for (int j = 0; j < 4; ++j) b[j] = *(const v4i*)(Brd + b_off[j]);
        __builtin_amdgcn_s_setprio(1);
#pragma unroll
        for (int i = 0; i < 8; ++i)
#pragma unroll
            for (int j = 0; j < 4; ++j)
                acc[i][j] = __builtin_amdgcn_mfma_i32_16x16x64_i8(a[i], b[j], acc[i][j], 0, 0, 0);
        __builtin_amdgcn_s_setprio(0);

        // stage B(t+1) mid-tile (other buffer; hazard-free: prior reads of
        // that buffer finished before last iteration's end barrier)
        if (t + 1 < KT) {
            int8_t* Bwr = smem + (((t + 1) & 1) << 16) + 32768;
#pragma unroll
            for (int q = 0; q < 4; ++q) gld16(Wt + bg[q] + kb1, Bwr + ldso[q]);
        }

        // ---- ksub 1 ----
#pragma unroll
        for (int i = 0; i < 8; ++i) a[i] = *(const v4i*)(Ard + (a_off[i] ^ 64));
#pragma unroll
        for (int j = 0; j < 4; ++j) b[j] = *(const v4i*)(Brd + (b_off[j] ^ 64));
        __builtin_amdgcn_s_setprio(1);
#pragma unroll
        for (int i = 0; i < 8; ++i)
#pragma unroll
            for (int j = 0; j < 4; ++j)
                acc[i][j] = __builtin_amdgcn_mfma_i32_16x16x64_i8(a[i], b[j], acc[i][j], 0, 0, 0);
        __builtin_amdgcn_s_setprio(0);

        asm volatile("s_barrier" ::: "memory");  // all reads of tile t done
    }

    // ---- epilogue: y = alpha*acc + bias ----
    // C/D layout (m89, dtype-independent): col = lane&15, row = quad*4 + reg
    const float alpha = *alphap;
#pragma unroll
    for (int j = 0; j < 4; ++j) {
        const int col = n0 + wn + j * 16 + lrow;
        const float bj = bias[col];
#pragma unroll
        for (int i = 0; i < 8; ++i) {
            const size_t rbase = (size_t)(m0 + wm + i * 16 + quad * 4) * N_DIM + col;
#pragma unroll
            for (int r = 0; r < 4; ++r)
                Y[rbase + (size_t)r * N_DIM] = fmaf(alpha, (float)acc[i][j][r], bj);
        }
    }
}

// ---------------- 128x128 kernel (known-good, fallback if attr fails) ------
__global__ __launch_bounds__(256) void w8a8_gemm_packed(
    const int8_t* __restrict__ X,
    const int8_t* __restrict__ Wt,
    const float*  __restrict__ bias,
    const float*  __restrict__ alphap,
    float* __restrict__ Y)
{
    __shared__ __align__(16) int8_t As[TM * TK];
    __shared__ __align__(16) int8_t Bs[TN * TK];

    const int tid  = threadIdx.x;
    const int lane = tid & 63;
    const int wave = tid >> 6;

    const int m0 = blockIdx.x * TM;
    const int n0 = blockIdx.y * TN;

    const int8_t* Aga[4];
    const int8_t* Bga[4];
    int lds_off[4];
#pragma unroll
    for (int i = 0; i < 4; ++i) {
        const int c    = (wave * 4 + i) * 64 + lane;
        const int row  = c >> 3;
        const int gko  = ((c & 7) ^ ((row >> 1) & 7)) << 4;
        Aga[i] = X  + (size_t)(m0 + row) * K_DIM + gko;
        Bga[i] = Wt + (size_t)(n0 + row) * K_DIM + gko;
        lds_off[i] = c << 4;
    }

    const int wm   = (wave & 1) << 6;
    const int wn   = (wave >> 1) << 6;
    const int lrow = lane & 15;
    const int quad = lane >> 4;

    int a_off[4], b_off[4];
#pragma unroll
    for (int i = 0; i < 4; ++i) {
        const int ra = wm + i * 16 + lrow;
        a_off[i] = ra * TK + ((quad ^ ((ra >> 1) & 7)) << 4);
        const int rb = wn + i * 16 + lrow;
        b_off[i] = rb * TK + ((quad ^ ((rb >> 1) & 7)) << 4);
    }

    v4i acc[4][4] = {};

    for (int kt = 0; kt < KSTEPS; ++kt) {
        const int kb = kt * TK;
#pragma unroll
        for (int i = 0; i < 4; ++i) {
            gld16(Aga[i] + kb, As + lds_off[i]);
            gld16(Bga[i] + kb, Bs + lds_off[i]);
        }
        __syncthreads();

#pragma unroll
        for (int kk = 0; kk < 2; ++kk) {
            const int kx = kk << 6;
            v4i a[4], b[4];
#pragma unroll
            for (int i = 0; i < 4; ++i) a[i] = *(const v4i*)(As + (a_off[i] ^ kx));
#pragma unroll
            for (int j = 0; j < 4; ++j) b[j] = *(const v4i*)(Bs + (b_off[j] ^ kx));
#pragma unroll
            for (int i = 0; i < 4; ++i)
#pragma unroll
                for (int j = 0; j < 4; ++j)
                    acc[i][j] = __builtin_amdgcn_mfma_i32_16x16x64_i8(a[i], b[j], acc[i][j], 0, 0, 0);
        }

        __syncthreads();
    }

    const float alpha = *alphap;
#pragma unroll
    for (int j = 0; j < 4; ++j) {
        const int col = n0 + wn + j * 16 + lrow;
        const float bj = bias[col];
#pragma unroll
        for (int i = 0; i < 4; ++i) {
            const size_t rbase = (size_t)(m0 + wm + i * 16 + quad * 4) * N_DIM + col;
#pragma unroll
            for (int r = 0; r < 4; ++r)
                Y[rbase + (size_t)r * N_DIM] = fmaf(alpha, (float)acc[i][j][r], bj);
        }
    }
}

// ---------------- fallback (round-2 kernel, known-good, no ws needed) ------
__global__ __launch_bounds__(256, 2) void w8a8_gemm_fb(
    const int*   __restrict__ X,
    const int*   __restrict__ Wt,
    const float* __restrict__ bias,
    const float* __restrict__ alphap,
    float* __restrict__ Y)
{
    __shared__ __align__(16) int8_t As[TM * 64];
    __shared__ __align__(16) int8_t Bs[TN * 64];

    const int tid  = threadIdx.x;
    const int lane = tid & 63;
    const int wave = tid >> 6;
    const int m0 = blockIdx.x * TM;
    const int n0 = blockIdx.y * TN;

    const int srow = tid >> 3;
    const int sk   = (tid & 7) * 8;
    const int* Ag = X  + (size_t)(m0 + srow) * K_DIM + sk;
    const int* Bg = Wt + (size_t)(n0 + srow) * K_DIM + sk;

    int wr_off[4];
#pragma unroll
    for (int r = 0; r < 4; ++r) {
        const int row = r * 32 + (tid >> 3);
        const int dw  = (tid & 7) * 2;
        const int sw  = row * 16 + (((dw >> 2) ^ ((row >> 1) & 3)) << 2) + (dw & 3);
        wr_off[r] = sw * 4;
    }

    const int wm   = (wave & 1) << 6;
    const int wn   = (wave >> 1) << 6;
    const int lrow = lane & 15;
    const int quad = lane >> 4;

    int a_off[4], b_off[4];
#pragma unroll
    for (int i = 0; i < 4; ++i) {
        const int ra = wm + i * 16 + lrow;
        a_off[i] = ra * 64 + ((quad ^ ((ra >> 1) & 3)) << 4);
        const int rb = wn + i * 16 + lrow;
        b_off[i] = rb * 64 + ((quad ^ ((rb >> 1) & 3)) << 4);
    }

    v4i acc[4][4] = {};
    v4i av[8], bv[8];
#pragma unroll
    for (int r = 0; r < 4; ++r) {
        const int* pa = Ag + (size_t)r * 32 * K_DIM;
        const int* pb = Bg + (size_t)r * 32 * K_DIM;
        av[2 * r] = *(const v4i*)(pa);  av[2 * r + 1] = *(const v4i*)(pa + 4);
        bv[2 * r] = *(const v4i*)(pb);  bv[2 * r + 1] = *(const v4i*)(pb + 4);
    }

    for (int kt = 0; kt < 64; ++kt) {
#pragma unroll
        for (int r = 0; r < 4; ++r) {
            int2 pa2, pb2;
            pa2.x = pack4(av[2*r].x,   av[2*r].y,   av[2*r].z,   av[2*r].w);
            pa2.y = pack4(av[2*r+1].x, av[2*r+1].y, av[2*r+1].z, av[2*r+1].w);
            pb2.x = pack4(bv[2*r].x,   bv[2*r].y,   bv[2*r].z,   bv[2*r].w);
            pb2.y = pack4(bv[2*r+1].x, bv[2*r+1].y, bv[2*r+1].z, bv[2*r+1].w);
            *(int2*)(As + wr_off[r]) = pa2;
            *(int2*)(Bs + wr_off[r]) = pb2;
        }
        const int kn = (kt + 1 < 64) ? (kt + 1) : kt;
        const int koff = kn * 64;
#pragma unroll
        for (int r = 0; r < 4; ++r) {
            const int* pa = Ag + (size_t)r * 32 * K_DIM + koff;
            const int* pb = Bg + (size_t)r * 32 * K_DIM + koff;
            av[2 * r] = *(const v4i*)(pa);  av[2 * r + 1] = *(const v4i*)(pa + 4);
            bv[2 * r] = *(const v4i*)(pb);  bv[2 * r + 1] = *(const v4i*)(pb + 4);
        }
        __syncthreads();
        v4i a[4], b[4];
#pragma unroll
        for (int i = 0; i < 4; ++i) a[i] = *(const v4i*)(As + a_off[i]);
#pragma unroll
        for (int j = 0; j < 4; ++j) b[j] = *(const v4i*)(Bs + b_off[j]);
#pragma unroll
        for (int i = 0; i < 4; ++i)
#pragma unroll
            for (int j = 0; j < 4; ++j)
                acc[i][j] = __builtin_amdgcn_mfma_i32_16x16x64_i8(a[i], b[j], acc[i][j], 0, 0, 0);
        __syncthreads();
    }

    const float alpha = *alphap;
#pragma unroll
    for (int j = 0; j < 4; ++j) {
        const int col = n0 + wn + j * 16 + lrow;
        const float bj = bias[col];
#pragma unroll
        for (int i = 0; i < 4; ++i) {
            const size_t rbase = (size_t)(m0 + wm + i * 16 + quad * 4) * N_DIM + col;
#pragma unroll
            for (int r = 0; r < 4; ++r)
                Y[rbase + (size_t)r * N_DIM] = fmaf(alpha, (float)acc[i][j][r], bj);
        }
    }
}

extern "C" void kernel_launch(void* const* d_in, const int* in_sizes, int n_in,
                              void* d_out, int out_size, void* d_ws, size_t ws_size,
                              hipStream_t stream) {
    const int*   X32   = (const int*)d_in[0];     // [4,2048,4096] int8-in-int32
    const int*   W32   = (const int*)d_in[1];     // [4096,4096]  int8-in-int32
    const float* bias  = (const float*)d_in[2];   // [1,4096] fp32
    const float* alpha = (const float*)d_in[3];   // scalar fp32
    float* Y = (float*)d_out;                     // [4,2048,4096] fp32

    const int nX = in_sizes[0];                   // 33554432
    const int nW = in_sizes[1];                   // 16777216
    const int M  = nX / K_DIM;                    // 8192

    if (ws_size >= (size_t)nX + (size_t)nW) {
        int8_t* Xp = (int8_t*)d_ws;
        int8_t* Wp = Xp + nX;
        const int n1 = nX / 4, n2 = nW / 4;
        const int nthreads = n1 + n2;
        pack_both<<<(nthreads + 255) / 256, 256, 0, stream>>>(
            X32, (int*)Xp, n1, W32, (int*)Wp, n2);

        // 128 KB dynamic LDS needs the opt-in attribute (set once)
        static hipError_t attr = hipFuncSetAttribute(
            reinterpret_cast<const void*>(w8a8_gemm_256),
            hipFuncAttributeMaxDynamicSharedMemorySize, 131072);

        if (attr == hipSuccess && (M % BM) == 0) {
            const int nblocks = (M / BM) * (N_DIM / BN);   // 32*16 = 512
            w8a8_gemm_256<<<dim3(nblocks), dim3(512), 131072, stream>>>(
                Xp, Wp, bias, alpha, Y);
        } else {
            dim3 grid(M / TM, N_DIM / TN);
            w8a8_gemm_packed<<<grid, dim3(256), 0, stream>>>(Xp, Wp, bias, alpha, Y);
        }
    } else {
        dim3 grid(M / TM, N_DIM / TN);
        w8a8_gemm_fb<<<grid, dim3(256), 0, stream>>>(X32, W32, bias, alpha, Y);
    }
}

// Round 2
// 388.519 us; speedup vs baseline: 1.0733x; 1.0079x over previous
//
#include <hip/hip_runtime.h>
#include <stdint.h>

typedef int v4i __attribute__((ext_vector_type(4)));

constexpr int K_DIM = 4096;
constexpr int N_DIM = 4096;
constexpr int TM = 128;
constexpr int TN = 128;
constexpr int TK = 128;              // two i8 MFMA K-steps per barrier pair
constexpr int KSTEPS = K_DIM / TK;   // 32

// pack low bytes of 4 int32 (each holding one int8 value) into one dword
__device__ __forceinline__ int pack4(int a, int b, int c, int d) {
    unsigned r = (unsigned(a) & 0xFFu)
               | ((unsigned(b) & 0xFFu) << 8)
               | ((unsigned(c) & 0xFFu) << 16)
               | (unsigned(d) << 24);
    return (int)r;
}

// ---------------- pre-pack: int8-in-int32 -> packed int8 (fused X+W) -------
__global__ __launch_bounds__(256) void pack_both(
    const int* __restrict__ s1, int* __restrict__ d1, int n1,   // dwords out
    const int* __restrict__ s2, int* __restrict__ d2, int n2)
{
    int idx = blockIdx.x * blockDim.x + threadIdx.x;
    const int* s;
    int* d;
    if (idx < n1) { s = s1; d = d1; }
    else if (idx < n1 + n2) { s = s2; d = d2; idx -= n1; }
    else return;
    v4i v = ((const v4i*)s)[idx];
    d[idx] = pack4(v.x, v.y, v.z, v.w);
}

// async global->LDS, 16 B per lane. LDS dest = wave-uniform base + lane*16.
__device__ __forceinline__ void gld16(const int8_t* g, int8_t* l) {
    __builtin_amdgcn_global_load_lds(
        (const __attribute__((address_space(1))) char*)g,
        (__attribute__((address_space(3))) char*)l,
        16, 0, 0);
}

// ============ 256x256 8-wave, K-half ring pipeline (T1+T3+T4+T5) ============
// C[m][n] = alpha * sum_k X[m][k]*W[n][k] + bias[n]
// 8 waves (2M x 4N), per-wave output 128x64 = 8x4 frags of 16x16, K-step 64.
// Staging unit = K-half: {A 256rows x 64B, B 256rows x 64B} = 32 KB.
// Ring of 4 units = 128 KB LDS. While computing k-half h, units h+1/h+2 are
// in flight and h+3 is being issued -> s_waitcnt vmcnt(8) at each k-half top
// (never drains in main loop). One raw s_barrier per k-half: it is both the
// "h visible" fence (after vmcnt) and the "h-1 reads done" fence (lgkm
// drained by MFMA uses) before h+3 overwrites unit (h-1)&3.
// Per-unit LDS swizzle (proven conflict-free, fb-kernel layout):
//   slot s of row r holds global k-chunk s ^ ((r>>1)&3); fragment read
//   offset = row*64 + ((quad ^ ((row>>1)&3))<<4).
constexpr int BM = 256;
constexpr int BN = 256;
constexpr int HKB = 64;              // K-half bytes
constexpr int NH = K_DIM / HKB;      // 64 k-halves

__global__ __launch_bounds__(512, 2) void w8a8_gemm_256p(
    const int8_t* __restrict__ X,     // [M][K] int8 packed
    const int8_t* __restrict__ Wt,    // [N][K] int8 packed (B^T)
    const float*  __restrict__ bias,  // [N]
    const float*  __restrict__ alphap,
    float* __restrict__ Y)            // [M][N] fp32
{
    extern __shared__ __align__(128) int8_t smem[];   // 4 x {A 16K, B 16K}

    const int tid  = threadIdx.x;
    const int lane = tid & 63;
    const int wave = tid >> 6;

    // XCD-aware bijective swizzle: 512 blocks, 64 per XCD
    const int flat = blockIdx.x;
    const int swz  = (flat & 7) * 64 + (flat >> 3);
    const int m0   = (swz & 31) * BM;
    const int n0   = (swz >> 5) * BN;

    // ---- staging geometry: per k-half, A = 1024 chunks = 2 rounds x 512 ----
    int ga[2], gb[2], ls[2];          // 32-bit offsets (max ~33.5M < 2^31)
#pragma unroll
    for (int q = 0; q < 2; ++q) {
        const int c   = q * 512 + tid;
        const int row = c >> 2;
        const int sl  = ((c & 3) ^ ((row >> 1) & 3)) << 4;
        ga[q] = (m0 + row) * K_DIM + sl;
        gb[q] = (n0 + row) * K_DIM + sl;
        ls[q] = c << 4;
    }

    // ---- compute geometry ----
    const int wm   = (wave & 1) << 7;   // 0 / 128
    const int wn   = (wave >> 1) << 6;  // 0 / 64 / 128 / 192
    const int lrow = lane & 15;
    const int quad = lane >> 4;

    int a_off[8], b_off[4];             // offsets within a 32 KB unit
#pragma unroll
    for (int i = 0; i < 8; ++i) {
        const int ra = wm + i * 16 + lrow;
        a_off[i] = ra * HKB + ((quad ^ ((ra >> 1) & 3)) << 4);
    }
#pragma unroll
    for (int j = 0; j < 4; ++j) {
        const int rb = wn + j * 16 + lrow;
        b_off[j] = 16384 + rb * HKB + ((quad ^ ((rb >> 1) & 3)) << 4);
    }

    v4i acc[8][4] = {};

    // ---- prologue: issue k-halves 0,1,2 (12 gld16 in flight) ----
#pragma unroll
    for (int p = 0; p < 3; ++p) {
        int8_t* ib = smem + (p << 15);
        const int kb = p * HKB;
        gld16(X  + ga[0] + kb, ib + ls[0]);
        gld16(X  + ga[1] + kb, ib + ls[1]);
        gld16(Wt + gb[0] + kb, ib + 16384 + ls[0]);
        gld16(Wt + gb[1] + kb, ib + 16384 + ls[1]);
    }

    // one k-half: wait(h landed) -> barrier -> issue A(h+3) -> reads+16 MFMA
    //             -> issue B(h+3) -> reads+16 MFMA
#define KHALF_BODY(VMN, DOISS)                                               \
    {                                                                        \
        asm volatile("s_waitcnt vmcnt(" #VMN ")" ::: "memory");              \
        __builtin_amdgcn_s_barrier();                                        \
        int8_t* Ab = smem + ((h & 3) << 15);                                 \
        if (DOISS) {                                                         \
            int8_t* ib  = smem + (((h + 3) & 3) << 15);                      \
            const int k3 = (h + 3) * HKB;                                    \
            gld16(X + ga[0] + k3, ib + ls[0]);                               \
            gld16(X + ga[1] + k3, ib + ls[1]);                               \
        }                                                                    \
        v4i a[8], b[4];                                                      \
        _Pragma("unroll")                                                    \
        for (int i = 0; i < 4; ++i) a[i] = *(const v4i*)(Ab + a_off[i]);     \
        _Pragma("unroll")                                                    \
        for (int j = 0; j < 4; ++j) b[j] = *(const v4i*)(Ab + b_off[j]);     \
        __builtin_amdgcn_s_setprio(1);                                       \
        _Pragma("unroll")                                                    \
        for (int i = 0; i < 4; ++i)                                          \
            _Pragma("unroll")                                                \
            for (int j = 0; j < 4; ++j)                                      \
                acc[i][j] = __builtin_amdgcn_mfma_i32_16x16x64_i8(           \
                    a[i], b[j], acc[i][j], 0, 0, 0);                         \
        __builtin_amdgcn_s_setprio(0);                                       \
        if (DOISS) {                                                         \
            int8_t* ib  = smem + (((h + 3) & 3) << 15);                      \
            const int k3 = (h + 3) * HKB;                                    \
            gld16(Wt + gb[0] + k3, ib + 16384 + ls[0]);                      \
            gld16(Wt + gb[1] + k3, ib + 16384 + ls[1]);                      \
        }                                                                    \
        _Pragma("unroll")                                                    \
        for (int i = 4; i < 8; ++i) a[i] = *(const v4i*)(Ab + a_off[i]);     \
        __builtin_amdgcn_s_setprio(1);                                       \
        _Pragma("unroll")                                                    \
        for (int i = 4; i < 8; ++i)                                          \
            _Pragma("unroll")                                                \
            for (int j = 0; j < 4; ++j)                                      \
                acc[i][j] = __builtin_amdgcn_mfma_i32_16x16x64_i8(           \
                    a[i], b[j], acc[i][j], 0, 0, 0);                         \
        __builtin_amdgcn_s_setprio(0);                                       \
    }

    // main loop: h = 0..60 issue h+3 (last issued: 63), steady vmcnt(8)
#pragma unroll 1
    for (int h = 0; h < 61; ++h) KHALF_BODY(8, true)
    // tail: 61 (h+1,h+2 in flight = 8), 62 (4), 63 (0)
    { const int h = 61; KHALF_BODY(8, false) }
    { const int h = 62; KHALF_BODY(4, false) }
    { const int h = 63; KHALF_BODY(0, false) }
#undef KHALF_BODY

    // ---- epilogue: y = alpha*acc + bias ----
    // C/D layout (m89, dtype-independent): col = lane&15, row = quad*4 + reg
    const float alpha = *alphap;
#pragma unroll
    for (int j = 0; j < 4; ++j) {
        const int col = n0 + wn + j * 16 + lrow;
        const float bj = bias[col];
#pragma unroll
        for (int i = 0; i < 8; ++i) {
            const size_t rbase = (size_t)(m0 + wm + i * 16 + quad * 4) * N_DIM + col;
#pragma unroll
            for (int r = 0; r < 4; ++r)
                Y[rbase + (size_t)r * N_DIM] = fmaf(alpha, (float)acc[i][j][r], bj);
        }
    }
}

// ---------------- 128x128 kernel (known-good, fallback if attr fails) ------
__global__ __launch_bounds__(256) void w8a8_gemm_packed(
    const int8_t* __restrict__ X,
    const int8_t* __restrict__ Wt,
    const float*  __restrict__ bias,
    const float*  __restrict__ alphap,
    float* __restrict__ Y)
{
    __shared__ __align__(16) int8_t As[TM * TK];
    __shared__ __align__(16) int8_t Bs[TN * TK];

    const int tid  = threadIdx.x;
    const int lane = tid & 63;
    const int wave = tid >> 6;

    const int m0 = blockIdx.x * TM;
    const int n0 = blockIdx.y * TN;

    const int8_t* Aga[4];
    const int8_t* Bga[4];
    int lds_off[4];
#pragma unroll
    for (int i = 0; i < 4; ++i) {
        const int c    = (wave * 4 + i) * 64 + lane;
        const int row  = c >> 3;
        const int gko  = ((c & 7) ^ ((row >> 1) & 7)) << 4;
        Aga[i] = X  + (size_t)(m0 + row) * K_DIM + gko;
        Bga[i] = Wt + (size_t)(n0 + row) * K_DIM + gko;
        lds_off[i] = c << 4;
    }

    const int wm   = (wave & 1) << 6;
    const int wn   = (wave >> 1) << 6;
    const int lrow = lane & 15;
    const int quad = lane >> 4;

    int a_off[4], b_off[4];
#pragma unroll
    for (int i = 0; i < 4; ++i) {
        const int ra = wm + i * 16 + lrow;
        a_off[i] = ra * TK + ((quad ^ ((ra >> 1) & 7)) << 4);
        const int rb = wn + i * 16 + lrow;
        b_off[i] = rb * TK + ((quad ^ ((rb >> 1) & 7)) << 4);
    }

    v4i acc[4][4] = {};

    for (int kt = 0; kt < KSTEPS; ++kt) {
        const int kb = kt * TK;
#pragma unroll
        for (int i = 0; i < 4; ++i) {
            gld16(Aga[i] + kb, As + lds_off[i]);
            gld16(Bga[i] + kb, Bs + lds_off[i]);
        }
        __syncthreads();

#pragma unroll
        for (int kk = 0; kk < 2; ++kk) {
            const int kx = kk << 6;
            v4i a[4], b[4];
#pragma unroll
            for (int i = 0; i < 4; ++i) a[i] = *(const v4i*)(As + (a_off[i] ^ kx));
#pragma unroll
            for (int j = 0; j < 4; ++j) b[j] = *(const v4i*)(Bs + (b_off[j] ^ kx));
#pragma unroll
            for (int i = 0; i < 4; ++i)
#pragma unroll
                for (int j = 0; j < 4; ++j)
                    acc[i][j] = __builtin_amdgcn_mfma_i32_16x16x64_i8(a[i], b[j], acc[i][j], 0, 0, 0);
        }

        __syncthreads();
    }

    const float alpha = *alphap;
#pragma unroll
    for (int j = 0; j < 4; ++j) {
        const int col = n0 + wn + j * 16 + lrow;
        const float bj = bias[col];
#pragma unroll
        for (int i = 0; i < 4; ++i) {
            const size_t rbase = (size_t)(m0 + wm + i * 16 + quad * 4) * N_DIM + col;
#pragma unroll
            for (int r = 0; r < 4; ++r)
                Y[rbase + (size_t)r * N_DIM] = fmaf(alpha, (float)acc[i][j][r], bj);
        }
    }
}

// ---------------- fallback (round-2 kernel, known-good, no ws needed) ------
__global__ __launch_bounds__(256, 2) void w8a8_gemm_fb(
    const int*   __restrict__ X,
    const int*   __restrict__ Wt,
    const float* __restrict__ bias,
    const float* __restrict__ alphap,
    float* __restrict__ Y)
{
    __shared__ __align__(16) int8_t As[TM * 64];
    __shared__ __align__(16) int8_t Bs[TN * 64];

    const int tid  = threadIdx.x;
    const int lane = tid & 63;
    const int wave = tid >> 6;
    const int m0 = blockIdx.x * TM;
    const int n0 = blockIdx.y * TN;

    const int srow = tid >> 3;
    const int sk   = (tid & 7) * 8;
    const int* Ag = X  + (size_t)(m0 + srow) * K_DIM + sk;
    const int* Bg = Wt + (size_t)(n0 + srow) * K_DIM + sk;

    int wr_off[4];
#pragma unroll
    for (int r = 0; r < 4; ++r) {
        const int row = r * 32 + (tid >> 3);
        const int dw  = (tid & 7) * 2;
        const int sw  = row * 16 + (((dw >> 2) ^ ((row >> 1) & 3)) << 2) + (dw & 3);
        wr_off[r] = sw * 4;
    }

    const int wm   = (wave & 1) << 6;
    const int wn   = (wave >> 1) << 6;
    const int lrow = lane & 15;
    const int quad = lane >> 4;

    int a_off[4], b_off[4];
#pragma unroll
    for (int i = 0; i < 4; ++i) {
        const int ra = wm + i * 16 + lrow;
        a_off[i] = ra * 64 + ((quad ^ ((ra >> 1) & 3)) << 4);
        const int rb = wn + i * 16 + lrow;
        b_off[i] = rb * 64 + ((quad ^ ((rb >> 1) & 3)) << 4);
    }

    v4i acc[4][4] = {};
    v4i av[8], bv[8];
#pragma unroll
    for (int r = 0; r < 4; ++r) {
        const int* pa = Ag + (size_t)r * 32 * K_DIM;
        const int* pb = Bg + (size_t)r * 32 * K_DIM;
        av[2 * r] = *(const v4i*)(pa);  av[2 * r + 1] = *(const v4i*)(pa + 4);
        bv[2 * r] = *(const v4i*)(pb);  bv[2 * r + 1] = *(const v4i*)(pb + 4);
    }

    for (int kt = 0; kt < 64; ++kt) {
#pragma unroll
        for (int r = 0; r < 4; ++r) {
            int2 pa2, pb2;
            pa2.x = pack4(av[2*r].x,   av[2*r].y,   av[2*r].z,   av[2*r].w);
            pa2.y = pack4(av[2*r+1].x, av[2*r+1].y, av[2*r+1].z, av[2*r+1].w);
            pb2.x = pack4(bv[2*r].x,   bv[2*r].y,   bv[2*r].z,   bv[2*r].w);
            pb2.y = pack4(bv[2*r+1].x, bv[2*r+1].y, bv[2*r+1].z, bv[2*r+1].w);
            *(int2*)(As + wr_off[r]) = pa2;
            *(int2*)(Bs + wr_off[r]) = pb2;
        }
        const int kn = (kt + 1 < 64) ? (kt + 1) : kt;
        const int koff = kn * 64;
#pragma unroll
        for (int r = 0; r < 4; ++r) {
            const int* pa = Ag + (size_t)r * 32 * K_DIM + koff;
            const int* pb = Bg + (size_t)r * 32 * K_DIM + koff;
            av[2 * r] = *(const v4i*)(pa);  av[2 * r + 1] = *(const v4i*)(pa + 4);
            bv[2 * r] = *(const v4i*)(pb);  bv[2 * r + 1] = *(const v4i*)(pb + 4);
        }
        __syncthreads();
        v4i a[4], b[4];
#pragma unroll
        for (int i = 0; i < 4; ++i) a[i] = *(const v4i*)(As + a_off[i]);
#pragma unroll
        for (int j = 0; j < 4; ++j) b[j] = *(const v4i*)(Bs + b_off[j]);
#pragma unroll
        for (int i = 0; i < 4; ++i)
#pragma unroll
            for (int j = 0; j < 4; ++j)
                acc[i][j] = __builtin_amdgcn_mfma_i32_16x16x64_i8(a[i], b[j], acc[i][j], 0, 0, 0);
        __syncthreads();
    }

    const float alpha = *alphap;
#pragma unroll
    for (int j = 0; j < 4; ++j) {
        const int col = n0 + wn + j * 16 + lrow;
        const float bj = bias[col];
#pragma unroll
        for (int i = 0; i < 4; ++i) {
            const size_t rbase = (size_t)(m0 + wm + i * 16 + quad * 4) * N_DIM + col;
#pragma unroll
            for (int r = 0; r < 4; ++r)
                Y[rbase + (size_t)r * N_DIM] = fmaf(alpha, (float)acc[i][j][r], bj);
        }
    }
}

extern "C" void kernel_launch(void* const* d_in, const int* in_sizes, int n_in,
                              void* d_out, int out_size, void* d_ws, size_t ws_size,
                              hipStream_t stream) {
    const int*   X32   = (const int*)d_in[0];     // [4,2048,4096] int8-in-int32
    const int*   W32   = (const int*)d_in[1];     // [4096,4096]  int8-in-int32
    const float* bias  = (const float*)d_in[2];   // [1,4096] fp32
    const float* alpha = (const float*)d_in[3];   // scalar fp32
    float* Y = (float*)d_out;                     // [4,2048,4096] fp32

    const int nX = in_sizes[0];                   // 33554432
    const int nW = in_sizes[1];                   // 16777216
    const int M  = nX / K_DIM;                    // 8192

    if (ws_size >= (size_t)nX + (size_t)nW) {
        int8_t* Xp = (int8_t*)d_ws;
        int8_t* Wp = Xp + nX;
        const int n1 = nX / 4, n2 = nW / 4;
        const int nthreads = n1 + n2;
        pack_both<<<(nthreads + 255) / 256, 256, 0, stream>>>(
            X32, (int*)Xp, n1, W32, (int*)Wp, n2);

        // 128 KB dynamic LDS needs the opt-in attribute (set once)
        static hipError_t attr = hipFuncSetAttribute(
            reinterpret_cast<const void*>(w8a8_gemm_256p),
            hipFuncAttributeMaxDynamicSharedMemorySize, 131072);

        if (attr == hipSuccess && (M % BM) == 0) {
            const int nblocks = (M / BM) * (N_DIM / BN);   // 32*16 = 512
            w8a8_gemm_256p<<<dim3(nblocks), dim3(512), 131072, stream>>>(
                Xp, Wp, bias, alpha, Y);
        } else {
            dim3 grid(M / TM, N_DIM / TN);
            w8a8_gemm_packed<<<grid, dim3(256), 0, stream>>>(Xp, Wp, bias, alpha, Y);
        }
    } else {
        dim3 grid(M / TM, N_DIM / TN);
        w8a8_gemm_fb<<<grid, dim3(256), 0, stream>>>(X32, W32, bias, alpha, Y);
    }
}